// Round 1
// baseline (626.364 us; speedup 1.0000x reference)
//
#include <hip/hip_runtime.h>
#include <math.h>

// Problem constants (fixed by setup_inputs)
#define BB 4
#define CC 3
#define HH 720
#define WW 1280
#define KS 5
#define KK 25
#define RR 2

__global__ __launch_bounds__(256) void kpn_weighting_kernel(
    const float* __restrict__ data,    // [B, C, H, W]
    const float* __restrict__ kern,    // [B, K*K, H, W]
    float* __restrict__ out)           // [B, C, H, W]
{
    const int HW = HH * WW;
    int idx = blockIdx.x * blockDim.x + threadIdx.x;   // over B*H*W
    const int total = BB * HW;
    if (idx >= total) return;

    int b  = idx / HW;
    int hw = idx - b * HW;
    int h  = hw / WW;
    int w  = hw - h * WW;

    // ---- load 25 per-pixel weights (coalesced: lanes differ only in w) ----
    const float* kp = kern + (size_t)b * KK * HW + hw;
    float wt[KK];
    float m = -1e30f;
    #pragma unroll
    for (int t = 0; t < KK; ++t) {
        wt[t] = kp[(size_t)t * HW];
        m = fmaxf(m, wt[t]);
    }
    // ---- softmax in registers ----
    float s = 0.f;
    #pragma unroll
    for (int t = 0; t < KK; ++t) {
        wt[t] = __expf(wt[t] - m);
        s += wt[t];
    }
    float inv = 1.0f / s;
    #pragma unroll
    for (int t = 0; t < KK; ++t) wt[t] *= inv;

    // ---- 3 channels x 25 taps; data reuse served by L1/L2 ----
    #pragma unroll
    for (int c = 0; c < CC; ++c) {
        const float* dp = data + ((size_t)b * CC + c) * HW;
        float acc = 0.f;
        #pragma unroll
        for (int i = 0; i < KS; ++i) {
            int hh = h + i - RR;
            if (hh < 0 || hh >= HH) continue;
            const float* rowp = dp + (size_t)hh * WW;
            #pragma unroll
            for (int j = 0; j < KS; ++j) {
                int ww = w + j - RR;
                if (ww < 0 || ww >= WW) continue;
                acc = fmaf(rowp[ww], wt[i * KS + j], acc);
            }
        }
        out[((size_t)b * CC + c) * HW + hw] = acc;
    }
}

extern "C" void kernel_launch(void* const* d_in, const int* in_sizes, int n_in,
                              void* d_out, int out_size, void* d_ws, size_t ws_size,
                              hipStream_t stream) {
    const float* data = (const float*)d_in[0];
    const float* kern = (const float*)d_in[1];
    float* out = (float*)d_out;

    const int total = BB * HH * WW;           // 3,686,400 threads
    const int block = 256;
    const int grid = (total + block - 1) / block;  // 14,400 blocks
    kpn_weighting_kernel<<<grid, block, 0, stream>>>(data, kern, out);
}

// Round 3
// 515.217 us; speedup vs baseline: 1.2157x; 1.2157x over previous
//
#include <hip/hip_runtime.h>
#include <math.h>

// Problem constants (fixed by setup_inputs)
#define BB 4
#define CC 3
#define HH 720
#define WW 1280
#define KS 5
#define KK 25
#define RR 2
#define W4 (WW / 4)          // 320 float4-groups per row
#define HW (HH * WW)

typedef float f4 __attribute__((ext_vector_type(4)));   // native clang vector

__global__ __launch_bounds__(256) void kpn_weighting_v4(
    const float* __restrict__ data,    // [B, C, H, W]
    const float* __restrict__ kern,    // [B, K*K, H, W]
    float* __restrict__ out)           // [B, C, H, W]
{
    const int idx = blockIdx.x * blockDim.x + threadIdx.x;   // over B*H*W4
    const int total = BB * HH * W4;                          // 921,600
    if (idx >= total) return;

    const int b   = idx / (HH * W4);
    const int rem = idx - b * (HH * W4);
    const int h   = rem / W4;
    const int w0  = (rem - h * W4) * 4;                      // base column, %4 == 0

    // ---- load 25 per-pixel weight vectors (dwordx4, coalesced, nontemporal) ----
    const float* kp = kern + (size_t)b * KK * HW + (size_t)h * WW + w0;
    f4 kw[KK];
    #pragma unroll
    for (int t = 0; t < KK; ++t) {
        kw[t] = __builtin_nontemporal_load((const f4*)(kp + (size_t)t * HW));
    }

    // ---- softmax per lane-pixel (4 pixels in vector lanes) ----
    f4 m = kw[0];
    #pragma unroll
    for (int t = 1; t < KK; ++t) {
        m.x = fmaxf(m.x, kw[t].x); m.y = fmaxf(m.y, kw[t].y);
        m.z = fmaxf(m.z, kw[t].z); m.w = fmaxf(m.w, kw[t].w);
    }
    f4 s = {0.f, 0.f, 0.f, 0.f};
    #pragma unroll
    for (int t = 0; t < KK; ++t) {
        kw[t].x = __expf(kw[t].x - m.x); s.x += kw[t].x;
        kw[t].y = __expf(kw[t].y - m.y); s.y += kw[t].y;
        kw[t].z = __expf(kw[t].z - m.z); s.z += kw[t].z;
        kw[t].w = __expf(kw[t].w - m.w); s.w += kw[t].w;
    }
    const f4 inv = {1.f / s.x, 1.f / s.y, 1.f / s.z, 1.f / s.w};
    #pragma unroll
    for (int t = 0; t < KK; ++t) kw[t] *= inv;

    // ---- 3 channels x 5 rows; each row read as 3 aligned float4 (12 cols) ----
    #pragma unroll
    for (int c = 0; c < CC; ++c) {
        const float* dp = data + ((size_t)b * CC + c) * HW;
        f4 acc = {0.f, 0.f, 0.f, 0.f};
        #pragma unroll
        for (int i = 0; i < KS; ++i) {
            const int hh = h + i - RR;
            if (hh < 0 || hh >= HH) continue;
            const float* rp = dp + (size_t)hh * WW + w0;

            float rb[12];
            if (w0 >= 4) {               // left segment fully in-bounds iff w0 != 0
                const f4 v = *(const f4*)(rp - 4);
                rb[0] = v.x; rb[1] = v.y; rb[2] = v.z; rb[3] = v.w;
            } else {
                rb[0] = rb[1] = rb[2] = rb[3] = 0.f;
            }
            {
                const f4 v = *(const f4*)rp;
                rb[4] = v.x; rb[5] = v.y; rb[6] = v.z; rb[7] = v.w;
            }
            if (w0 + 7 < WW) {           // right segment fully in-bounds iff w0 != 1276
                const f4 v = *(const f4*)(rp + 4);
                rb[8] = v.x; rb[9] = v.y; rb[10] = v.z; rb[11] = v.w;
            } else {
                rb[8] = rb[9] = rb[10] = rb[11] = 0.f;
            }

            #pragma unroll
            for (int j = 0; j < KS; ++j) {
                const f4 wt = kw[i * KS + j];
                // lane-pixel l reads column w0 + l + (j-2)  -> rb[2 + j + l]
                acc.x = fmaf(rb[2 + j], wt.x, acc.x);
                acc.y = fmaf(rb[3 + j], wt.y, acc.y);
                acc.z = fmaf(rb[4 + j], wt.z, acc.z);
                acc.w = fmaf(rb[5 + j], wt.w, acc.w);
            }
        }
        __builtin_nontemporal_store(acc,
            (f4*)(out + ((size_t)b * CC + c) * HW + (size_t)h * WW + w0));
    }
}

extern "C" void kernel_launch(void* const* d_in, const int* in_sizes, int n_in,
                              void* d_out, int out_size, void* d_ws, size_t ws_size,
                              hipStream_t stream) {
    const float* data = (const float*)d_in[0];
    const float* kern = (const float*)d_in[1];
    float* out = (float*)d_out;

    const int total = BB * HH * W4;                 // 921,600 threads
    const int block = 256;
    const int grid = (total + block - 1) / block;   // 3,600 blocks
    kpn_weighting_v4<<<grid, block, 0, stream>>>(data, kern, out);
}